// Round 1
// baseline (305.871 us; speedup 1.0000x reference)
//
#include <hip/hip_runtime.h>
#include <hip/hip_bf16.h>
#include <math.h>

#define Hdim 768
#define Idim 3072
#define Tn   1024
#define En   8

using v4f     = __attribute__((ext_vector_type(4))) float;
using short8  = __attribute__((ext_vector_type(8))) short;
using short4v = __attribute__((ext_vector_type(4))) short;
using us8     = __attribute__((ext_vector_type(8))) unsigned short;

__device__ inline unsigned short f2bf(float f) {
    unsigned u = __float_as_uint(f);
    u += 0x7fffu + ((u >> 16) & 1u);   // RNE
    return (unsigned short)(u >> 16);
}

// ---------------- gate: logits (fp32), argmax, per-expert sum/sumsq ----------------
__global__ __launch_bounds__(256) void gate_kernel(
    const float* __restrict__ x, const float* __restrict__ gw, const float* __restrict__ gb,
    float* __restrict__ gsum, float* __restrict__ gsumsq,
    int* __restrict__ count, int* __restrict__ sel)
{
    __shared__ float gws[8 * 772];          // stride 772 -> conflict-free float4 reads
    __shared__ float lg[32][8];
    int tid = threadIdx.x;
    for (int i = tid; i < 8 * 768; i += 256) gws[(i / 768) * 772 + (i % 768)] = gw[i];
    __syncthreads();

    int tok = tid >> 3, e = tid & 7;
    long t = (long)blockIdx.x * 32 + tok;
    const float4* xp = (const float4*)(x + t * Hdim);
    const float4* gp = (const float4*)(gws + e * 772);
    float acc = 0.f;
#pragma unroll 8
    for (int i = 0; i < 192; i++) {
        float4 a = xp[i]; float4 b = gp[i];
        acc += a.x * b.x + a.y * b.y + a.z * b.z + a.w * b.w;
    }
    lg[tok][e] = acc + gb[e];
    __syncthreads();

    if (tid < 32) {                          // per-token argmax (first-max tie-break like top_k)
        float best = lg[tid][0]; int bi = 0;
        for (int j = 1; j < 8; j++) { float v = lg[tid][j]; if (v > best) { best = v; bi = j; } }
        sel[blockIdx.x * 32 + tid] = bi;
        atomicAdd(&count[bi], 1);
    }
    if (tid < 8) {                           // block-partial moments
        float s = 0.f, ss = 0.f;
        for (int t2 = 0; t2 < 32; t2++) { float v = lg[t2][tid]; s += v; ss += v * v; }
        atomicAdd(&gsum[tid], s);
        atomicAdd(&gsumsq[tid], ss);
    }
}

// ---------------- finalize: lb_loss + offsets/cursors ----------------
__global__ void finalize_kernel(const float* __restrict__ gsum, const float* __restrict__ gsumsq,
                                const int* __restrict__ count,
                                int* __restrict__ offsets, int* __restrict__ cursor,
                                float* __restrict__ out_lb)
{
    if (threadIdx.x == 0) {
        float accr = 0.f;
        for (int e = 0; e < 8; e++) {
            float mean = gsum[e] * (1.0f / 1024.0f);
            float var  = (gsumsq[e] - gsum[e] * mean) * (1.0f / 1023.0f);  // ddof=1
            accr += var / (mean * mean + 1e-8f);
        }
        out_lb[0] = 0.01f * accr * 0.125f;
        int off = 0;
        for (int e = 0; e < 8; e++) { offsets[e] = off; cursor[e] = off; off += count[e]; }
    }
}

// ---------------- scatter tokens into expert buckets ----------------
__global__ __launch_bounds__(256) void scatter_kernel(const int* __restrict__ sel,
                                                      int* __restrict__ cursor,
                                                      int* __restrict__ perm)
{
    int t = blockIdx.x * 256 + threadIdx.x;
    if (t < Tn) {
        int e = sel[t];
        int pos = atomicAdd(&cursor[e], 1);
        perm[pos] = t;
    }
}

// ---------------- init out with b2[sel[t]] (gemm2 atomically accumulates on top) ----------------
__global__ __launch_bounds__(256) void init_out_kernel(const float* __restrict__ b2,
                                                       const int* __restrict__ sel,
                                                       float* __restrict__ out)
{
    int t = blockIdx.x;
    int h = blockIdx.y * 256 + threadIdx.x;
    out[(long)t * Hdim + h] = b2[sel[t] * Hdim + h];
}

// ---------------- GEMM1: hmid = gelu(x[perm] @ w1[e]^T + b1[e]) -> bf16 ----------------
__global__ __launch_bounds__(256) void gemm1_kernel(
    const float* __restrict__ x, const float* __restrict__ w1, const float* __restrict__ b1,
    const int* __restrict__ count, const int* __restrict__ offsets,
    const int* __restrict__ perm, unsigned short* __restrict__ hmid)
{
    int e = blockIdx.z;
    int nloc = count[e];
    int m0 = blockIdx.y << 7;
    if (m0 >= nloc) return;
    int n0 = blockIdx.x << 7;
    int off = offsets[e];

    __shared__ unsigned short As[128 * 40];   // stride 40 bf16 (80B) -> <=2-way LDS conflicts
    __shared__ unsigned short Bs[128 * 40];

    int tid = threadIdx.x;
    int lane = tid & 63, wave = tid >> 6;
    int quad = lane >> 4, l16 = lane & 15;
    int wm = (wave >> 1) << 6, wn = (wave & 1) << 6;

    int kq = tid & 7;          // float4 slot within 32-elem K window
    int r0 = tid >> 3;         // base row 0..31

    const float* aptr[4];
    const float* bptr[4];
#pragma unroll
    for (int i = 0; i < 4; i++) {
        int m = m0 + r0 + 32 * i;
        int mm = m < nloc ? m : nloc - 1;
        int tokr = perm[off + mm];
        aptr[i] = x  + (long)tokr * Hdim + kq * 4;
        bptr[i] = w1 + ((long)e * Idim + n0 + r0 + 32 * i) * Hdim + kq * 4;
    }

    v4f acc[4][4];
#pragma unroll
    for (int i = 0; i < 4; i++)
#pragma unroll
        for (int j = 0; j < 4; j++) acc[i][j] = (v4f){0.f, 0.f, 0.f, 0.f};

    for (int kb = 0; kb < Hdim; kb += 32) {
#pragma unroll
        for (int i = 0; i < 4; i++) {
            float4 va = *(const float4*)(aptr[i] + kb);
            float4 vb = *(const float4*)(bptr[i] + kb);
            int r = r0 + 32 * i;
            short4v pa = { (short)f2bf(va.x), (short)f2bf(va.y), (short)f2bf(va.z), (short)f2bf(va.w) };
            short4v pb = { (short)f2bf(vb.x), (short)f2bf(vb.y), (short)f2bf(vb.z), (short)f2bf(vb.w) };
            *(short4v*)(As + r * 40 + kq * 4) = pa;
            *(short4v*)(Bs + r * 40 + kq * 4) = pb;
        }
        __syncthreads();
        short8 af[4], bfr[4];
#pragma unroll
        for (int i = 0; i < 4; i++) af[i]  = *(const short8*)(As + (wm + i * 16 + l16) * 40 + quad * 8);
#pragma unroll
        for (int j = 0; j < 4; j++) bfr[j] = *(const short8*)(Bs + (wn + j * 16 + l16) * 40 + quad * 8);
#pragma unroll
        for (int i = 0; i < 4; i++)
#pragma unroll
            for (int j = 0; j < 4; j++)
                acc[i][j] = __builtin_amdgcn_mfma_f32_16x16x32_bf16(af[i], bfr[j], acc[i][j], 0, 0, 0);
        __syncthreads();
    }

#pragma unroll
    for (int i = 0; i < 4; i++) {
#pragma unroll
        for (int r = 0; r < 4; r++) {
            int m = m0 + wm + i * 16 + quad * 4 + r;
            if (m >= nloc) continue;
            long slot = off + m;
#pragma unroll
            for (int j = 0; j < 4; j++) {
                int n = n0 + wn + j * 16 + l16;
                float v = acc[i][j][r] + b1[e * Idim + n];
                float g = 0.5f * v * (1.0f + erff(v * 0.70710678118654752f));  // exact gelu
                hmid[slot * Idim + n] = f2bf(g);
            }
        }
    }
}

// ---------------- GEMM2 (split-K=4): out[t] += hmid[slot] @ w2[e]^T ----------------
__global__ __launch_bounds__(256) void gemm2_kernel(
    const unsigned short* __restrict__ hmid, const float* __restrict__ w2,
    const int* __restrict__ count, const int* __restrict__ offsets,
    const int* __restrict__ perm, float* __restrict__ out)
{
    int e = blockIdx.z;
    int nloc = count[e];
    int m0 = blockIdx.y << 7;
    if (m0 >= nloc) return;
    int ntile = blockIdx.x % 6;
    int kc    = blockIdx.x / 6;         // split-K chunk, 4 x 768
    int n0 = ntile << 7;
    int off = offsets[e];
    long kbase = (long)kc * 768;

    __shared__ unsigned short As[128 * 40];
    __shared__ unsigned short Bs[128 * 40];

    int tid = threadIdx.x;
    int lane = tid & 63, wave = tid >> 6;
    int quad = lane >> 4, l16 = lane & 15;
    int wm = (wave >> 1) << 6, wn = (wave & 1) << 6;

    // A staging: bf16 source, 16B chunks; 512 chunks / 256 thr = 2 each
    const unsigned short* aptr[2];
    int ar[2], aq[2];
#pragma unroll
    for (int i = 0; i < 2; i++) {
        int s = tid + (i << 8);
        int r = s >> 2, q = s & 3;
        int m = m0 + r; int mm = m < nloc ? m : nloc - 1;
        aptr[i] = hmid + (long)(off + mm) * Idim + kbase + q * 8;
        ar[i] = r; aq[i] = q;
    }
    int kq = tid & 7, r0 = tid >> 3;
    const float* bptr[4];
#pragma unroll
    for (int i = 0; i < 4; i++)
        bptr[i] = w2 + ((long)e * Hdim + n0 + r0 + 32 * i) * Idim + kbase + kq * 4;

    v4f acc[4][4];
#pragma unroll
    for (int i = 0; i < 4; i++)
#pragma unroll
        for (int j = 0; j < 4; j++) acc[i][j] = (v4f){0.f, 0.f, 0.f, 0.f};

    for (int kb = 0; kb < 768; kb += 32) {
#pragma unroll
        for (int i = 0; i < 2; i++) {
            us8 v = *(const us8*)(aptr[i] + kb);
            *(us8*)(As + ar[i] * 40 + aq[i] * 8) = v;
        }
#pragma unroll
        for (int i = 0; i < 4; i++) {
            float4 vb = *(const float4*)(bptr[i] + kb);
            int r = r0 + 32 * i;
            short4v pb = { (short)f2bf(vb.x), (short)f2bf(vb.y), (short)f2bf(vb.z), (short)f2bf(vb.w) };
            *(short4v*)(Bs + r * 40 + kq * 4) = pb;
        }
        __syncthreads();
        short8 af[4], bfr[4];
#pragma unroll
        for (int i = 0; i < 4; i++) af[i]  = *(const short8*)(As + (wm + i * 16 + l16) * 40 + quad * 8);
#pragma unroll
        for (int j = 0; j < 4; j++) bfr[j] = *(const short8*)(Bs + (wn + j * 16 + l16) * 40 + quad * 8);
#pragma unroll
        for (int i = 0; i < 4; i++)
#pragma unroll
            for (int j = 0; j < 4; j++)
                acc[i][j] = __builtin_amdgcn_mfma_f32_16x16x32_bf16(af[i], bfr[j], acc[i][j], 0, 0, 0);
        __syncthreads();
    }

#pragma unroll
    for (int i = 0; i < 4; i++) {
#pragma unroll
        for (int r = 0; r < 4; r++) {
            int m = m0 + wm + i * 16 + quad * 4 + r;
            if (m >= nloc) continue;
            int t = perm[off + m];
#pragma unroll
            for (int j = 0; j < 4; j++) {
                int n = n0 + wn + j * 16 + l16;
                atomicAdd(out + (long)t * Hdim + n, acc[i][j][r]);
            }
        }
    }
}

extern "C" void kernel_launch(void* const* d_in, const int* in_sizes, int n_in,
                              void* d_out, int out_size, void* d_ws, size_t ws_size,
                              hipStream_t stream)
{
    const float* x  = (const float*)d_in[0];
    const float* gw = (const float*)d_in[1];
    const float* gb = (const float*)d_in[2];
    const float* w1 = (const float*)d_in[3];
    const float* b1 = (const float*)d_in[4];
    const float* w2 = (const float*)d_in[5];
    const float* b2 = (const float*)d_in[6];
    float* out = (float*)d_out;

    // ws layout: [0:8) gsum f32, [8:16) gsumsq f32, ints: [16:24) count, [24:32) offsets,
    // [32:40) cursor, [40:1064) sel, [1064:2088) perm; hmid bf16 @ byte 8704 (6.29 MB)
    float* gsum    = (float*)d_ws;
    float* gsumsq  = gsum + 8;
    int*   count   = (int*)d_ws + 16;
    int*   offsets = (int*)d_ws + 24;
    int*   cursor  = (int*)d_ws + 32;
    int*   sel     = (int*)d_ws + 40;
    int*   perm    = (int*)d_ws + 40 + 1024;
    unsigned short* hmid = (unsigned short*)((char*)d_ws + 8704);

    hipMemsetAsync(d_ws, 0, 160, stream);
    gate_kernel<<<32, 256, 0, stream>>>(x, gw, gb, gsum, gsumsq, count, sel);
    finalize_kernel<<<1, 64, 0, stream>>>(gsum, gsumsq, count, offsets, cursor, out + (long)Tn * Hdim);
    scatter_kernel<<<4, 256, 0, stream>>>(sel, cursor, perm);
    init_out_kernel<<<dim3(Tn, 3), 256, 0, stream>>>(b2, sel, out);
    gemm1_kernel<<<dim3(24, 8, 8), 256, 0, stream>>>(x, w1, b1, count, offsets, perm, hmid);
    gemm2_kernel<<<dim3(24, 8, 8), 256, 0, stream>>>(hmid, w2, count, offsets, perm, out);
}

// Round 2
// 300.516 us; speedup vs baseline: 1.0178x; 1.0178x over previous
//
#include <hip/hip_runtime.h>
#include <hip/hip_bf16.h>
#include <math.h>

#define Hdim 768
#define Idim 3072
#define Tn   1024
#define En   8
#define LD1  72    // LDS stride (shorts) for BK=64 tiles: 144 B = 36 banks ≡ 4 (mod 32)
#define LD2  136   // LDS stride (shorts) for BK=128 tiles: 272 B = 68 banks ≡ 4 (mod 32)

using v4f     = __attribute__((ext_vector_type(4))) float;
using short8  = __attribute__((ext_vector_type(8))) short;
using short4v = __attribute__((ext_vector_type(4))) short;
using us8     = __attribute__((ext_vector_type(8))) unsigned short;

__device__ inline unsigned short f2bf(float f) {
    unsigned u = __float_as_uint(f);
    u += 0x7fffu + ((u >> 16) & 1u);   // RNE
    return (unsigned short)(u >> 16);
}
__device__ inline short4v pack4(float4 v) {
    return short4v{ (short)f2bf(v.x), (short)f2bf(v.y), (short)f2bf(v.z), (short)f2bf(v.w) };
}

// ---------------- gate: logits (fp32), argmax, per-expert sum/sumsq ----------------
__global__ __launch_bounds__(256) void gate_kernel(
    const float* __restrict__ x, const float* __restrict__ gw, const float* __restrict__ gb,
    float* __restrict__ gsum, float* __restrict__ gsumsq,
    int* __restrict__ count, int* __restrict__ sel)
{
    __shared__ float xs[16 * 772];
    __shared__ float gws[8 * 772];
    __shared__ float lg[16][8];
    int tid = threadIdx.x;
    long t0 = (long)blockIdx.x * 16;

    for (int i = tid; i < 8 * 768; i += 256) gws[(i / 768) * 772 + (i % 768)] = gw[i];
    for (int q = tid; q < 16 * 192; q += 256) {           // 192 float4 per row
        int row = q / 192, col = q % 192;
        ((float4*)(xs + row * 772))[col] = ((const float4*)(x + (t0 + row) * Hdim))[col];
    }
    __syncthreads();

    int t4 = tid >> 4, e = (tid >> 1) & 7, half = tid & 1;
    const float4* xp = (const float4*)(xs + t4 * 772) + half * 96;
    const float4* gp = (const float4*)(gws + e * 772) + half * 96;
    float a0 = 0.f, a1 = 0.f;
#pragma unroll 8
    for (int i = 0; i < 96; i += 2) {
        float4 xa = xp[i], ga = gp[i], xb = xp[i + 1], gb4 = gp[i + 1];
        a0 += xa.x * ga.x + xa.y * ga.y + xa.z * ga.z + xa.w * ga.w;
        a1 += xb.x * gb4.x + xb.y * gb4.y + xb.z * gb4.z + xb.w * gb4.w;
    }
    float acc = a0 + a1;
    acc += __shfl_xor(acc, 1);
    if (half == 0) lg[t4][e] = acc + gb[e];
    __syncthreads();

    if (tid < 16) {
        float best = lg[tid][0]; int bi = 0;
        for (int j = 1; j < 8; j++) { float v = lg[tid][j]; if (v > best) { best = v; bi = j; } }
        sel[t0 + tid] = bi;
        atomicAdd(&count[bi], 1);
    }
    if (tid < 8) {
        float s = 0.f, ss = 0.f;
        for (int t2 = 0; t2 < 16; t2++) { float v = lg[t2][tid]; s += v; ss += v * v; }
        atomicAdd(&gsum[tid], s);
        atomicAdd(&gsumsq[tid], ss);
    }
}

// ---------------- finalize: lb_loss + offsets/cursors ----------------
__global__ void finalize_kernel(const float* __restrict__ gsum, const float* __restrict__ gsumsq,
                                const int* __restrict__ count,
                                int* __restrict__ offsets, int* __restrict__ cursor,
                                float* __restrict__ out_lb)
{
    if (threadIdx.x == 0) {
        float accr = 0.f;
        for (int e = 0; e < 8; e++) {
            float mean = gsum[e] * (1.0f / 1024.0f);
            float var  = (gsumsq[e] - gsum[e] * mean) * (1.0f / 1023.0f);  // ddof=1
            accr += var / (mean * mean + 1e-8f);
        }
        out_lb[0] = 0.01f * accr * 0.125f;
        int off = 0;
        for (int e = 0; e < 8; e++) { offsets[e] = off; cursor[e] = off; off += count[e]; }
    }
}

// ---------------- scatter tokens into expert buckets ----------------
__global__ __launch_bounds__(256) void scatter_kernel(const int* __restrict__ sel,
                                                      int* __restrict__ cursor,
                                                      int* __restrict__ perm)
{
    int t = blockIdx.x * 256 + threadIdx.x;
    if (t < Tn) {
        int e = sel[t];
        int pos = atomicAdd(&cursor[e], 1);
        perm[pos] = t;
    }
}

// ---------------- GEMM1: hmid = gelu(x[perm] @ w1[e]^T + b1[e]) -> bf16 ----------------
// tile 128(M) x 64(N), BK=64, grid (48, 2, 8)
__global__ __launch_bounds__(256) void gemm1_kernel(
    const float* __restrict__ x, const float* __restrict__ w1, const float* __restrict__ b1,
    const int* __restrict__ count, const int* __restrict__ offsets,
    const int* __restrict__ perm, unsigned short* __restrict__ hmid)
{
    int e = blockIdx.z;
    int nloc = count[e];
    int m0 = blockIdx.y << 7;
    if (m0 >= nloc) return;
    int n0 = blockIdx.x << 6;
    int off = offsets[e];

    __shared__ unsigned short As[128 * LD1];   // 18.4 KB
    __shared__ unsigned short Bs[64 * LD1];    //  9.2 KB

    int tid = threadIdx.x;
    int lane = tid & 63, wave = tid >> 6;
    int quad = lane >> 4, l16 = lane & 15;
    int wm = (wave >> 1) << 6, wn = (wave & 1) << 5;   // wave tile 64x32

    int kq = tid & 7, r0 = tid >> 3;                   // r0 in [0,32)

    const float* aptr[4];
#pragma unroll
    for (int rs = 0; rs < 4; rs++) {
        int m = m0 + r0 + 32 * rs;
        int mm = m < nloc ? m : nloc - 1;
        aptr[rs] = x + (long)perm[off + mm] * Hdim + kq * 4;
    }
    const float* bptr[2];
#pragma unroll
    for (int rs = 0; rs < 2; rs++)
        bptr[rs] = w1 + ((long)e * Idim + n0 + r0 + 32 * rs) * Hdim + kq * 4;

    v4f acc[4][2];
#pragma unroll
    for (int i = 0; i < 4; i++)
#pragma unroll
        for (int j = 0; j < 2; j++) acc[i][j] = (v4f){0.f, 0.f, 0.f, 0.f};

    for (int kb = 0; kb < Hdim; kb += 64) {
        float4 va[4][2], vb[2][2];
#pragma unroll
        for (int rs = 0; rs < 4; rs++)
#pragma unroll
            for (int j = 0; j < 2; j++) va[rs][j] = *(const float4*)(aptr[rs] + kb + 32 * j);
#pragma unroll
        for (int rs = 0; rs < 2; rs++)
#pragma unroll
            for (int j = 0; j < 2; j++) vb[rs][j] = *(const float4*)(bptr[rs] + kb + 32 * j);
        __syncthreads();   // all waves done reading previous tile
#pragma unroll
        for (int rs = 0; rs < 4; rs++)
#pragma unroll
            for (int j = 0; j < 2; j++)
                *(short4v*)(As + (r0 + 32 * rs) * LD1 + kq * 4 + 32 * j) = pack4(va[rs][j]);
#pragma unroll
        for (int rs = 0; rs < 2; rs++)
#pragma unroll
            for (int j = 0; j < 2; j++)
                *(short4v*)(Bs + (r0 + 32 * rs) * LD1 + kq * 4 + 32 * j) = pack4(vb[rs][j]);
        __syncthreads();
#pragma unroll
        for (int s = 0; s < 2; s++) {
            short8 af[4], bfr[2];
#pragma unroll
            for (int i = 0; i < 4; i++)
                af[i] = *(const short8*)(As + (wm + i * 16 + l16) * LD1 + s * 32 + quad * 8);
#pragma unroll
            for (int j = 0; j < 2; j++)
                bfr[j] = *(const short8*)(Bs + (wn + j * 16 + l16) * LD1 + s * 32 + quad * 8);
#pragma unroll
            for (int i = 0; i < 4; i++)
#pragma unroll
                for (int j = 0; j < 2; j++)
                    acc[i][j] = __builtin_amdgcn_mfma_f32_16x16x32_bf16(af[i], bfr[j], acc[i][j], 0, 0, 0);
        }
    }

#pragma unroll
    for (int i = 0; i < 4; i++) {
        int mr = wm + i * 16 + quad * 4;
#pragma unroll
        for (int r = 0; r < 4; r++) {
            int m = m0 + mr + r;
            if (m >= nloc) continue;
            long slot = off + m;
#pragma unroll
            for (int j = 0; j < 2; j++) {
                int n = n0 + wn + j * 16 + l16;
                float v = acc[i][j][r] + b1[e * Idim + n];
                float g = 0.5f * v * (1.0f + erff(v * 0.70710678118654752f));
                hmid[slot * Idim + n] = f2bf(g);
            }
        }
    }
}

// ---------------- GEMM2: out[t] = hmid[slot] @ w2[e]^T + b2[e] (full-K, no atomics) ----
// tile 128(M) x 32(N), BK=128, grid (24, 2, 8)
__global__ __launch_bounds__(256) void gemm2_kernel(
    const unsigned short* __restrict__ hmid, const float* __restrict__ w2,
    const float* __restrict__ b2,
    const int* __restrict__ count, const int* __restrict__ offsets,
    const int* __restrict__ perm, float* __restrict__ out)
{
    int e = blockIdx.z;
    int nloc = count[e];
    int m0 = blockIdx.y << 7;
    if (m0 >= nloc) return;
    int n0 = blockIdx.x << 5;
    int off = offsets[e];

    __shared__ unsigned short As[128 * LD2];   // 34.8 KB
    __shared__ unsigned short Bs[32 * LD2];    //  8.7 KB

    int tid = threadIdx.x;
    int lane = tid & 63, wave = tid >> 6;
    int quad = lane >> 4, l16 = lane & 15;
    int wm = wave << 5;                        // wave tile 32x32, waves stacked on M

    // A staging: 16 lanes x 16B = 256 B per row (bf16), 8 row-steps
    int kq16 = tid & 15, ra = tid >> 4;        // ra in [0,16)
    const unsigned short* aptr[8];
#pragma unroll
    for (int rs = 0; rs < 8; rs++) {
        int m = m0 + ra + 16 * rs;
        int mm = m < nloc ? m : nloc - 1;
        aptr[rs] = hmid + (long)(off + mm) * Idim + kq16 * 8;
    }
    // B staging: 32 rows x 128 fp32
    int kq = tid & 7, rb = tid >> 3;           // rb in [0,32)
    const float* bptr = w2 + ((long)e * Hdim + n0 + rb) * Idim + kq * 4;

    v4f acc[2][2];
#pragma unroll
    for (int i = 0; i < 2; i++)
#pragma unroll
        for (int j = 0; j < 2; j++) acc[i][j] = (v4f){0.f, 0.f, 0.f, 0.f};

    for (int kb = 0; kb < Idim; kb += 128) {
        us8 va[8];
#pragma unroll
        for (int rs = 0; rs < 8; rs++) va[rs] = *(const us8*)(aptr[rs] + kb);
        float4 vb[4];
#pragma unroll
        for (int j = 0; j < 4; j++) vb[j] = *(const float4*)(bptr + kb + 32 * j);
        __syncthreads();
#pragma unroll
        for (int rs = 0; rs < 8; rs++)
            *(us8*)(As + (ra + 16 * rs) * LD2 + kq16 * 8) = va[rs];
#pragma unroll
        for (int j = 0; j < 4; j++)
            *(short4v*)(Bs + rb * LD2 + kq * 4 + 32 * j) = pack4(vb[j]);
        __syncthreads();
#pragma unroll
        for (int s = 0; s < 4; s++) {
            short8 af[2], bfr[2];
#pragma unroll
            for (int i = 0; i < 2; i++)
                af[i] = *(const short8*)(As + (wm + i * 16 + l16) * LD2 + s * 32 + quad * 8);
#pragma unroll
            for (int j = 0; j < 2; j++)
                bfr[j] = *(const short8*)(Bs + (j * 16 + l16) * LD2 + s * 32 + quad * 8);
#pragma unroll
            for (int i = 0; i < 2; i++)
#pragma unroll
                for (int j = 0; j < 2; j++)
                    acc[i][j] = __builtin_amdgcn_mfma_f32_16x16x32_bf16(af[i], bfr[j], acc[i][j], 0, 0, 0);
        }
    }

#pragma unroll
    for (int i = 0; i < 2; i++) {
        int mr = wm + i * 16 + quad * 4;
#pragma unroll
        for (int r = 0; r < 4; r++) {
            int m = m0 + mr + r;
            if (m >= nloc) continue;
            int t = perm[off + m];
#pragma unroll
            for (int j = 0; j < 2; j++) {
                int n = n0 + j * 16 + l16;
                out[(long)t * Hdim + n] = acc[i][j][r] + b2[e * Hdim + n];
            }
        }
    }
}

extern "C" void kernel_launch(void* const* d_in, const int* in_sizes, int n_in,
                              void* d_out, int out_size, void* d_ws, size_t ws_size,
                              hipStream_t stream)
{
    const float* x  = (const float*)d_in[0];
    const float* gw = (const float*)d_in[1];
    const float* gb = (const float*)d_in[2];
    const float* w1 = (const float*)d_in[3];
    const float* b1 = (const float*)d_in[4];
    const float* w2 = (const float*)d_in[5];
    const float* b2 = (const float*)d_in[6];
    float* out = (float*)d_out;

    float* gsum    = (float*)d_ws;
    float* gsumsq  = gsum + 8;
    int*   count   = (int*)d_ws + 16;
    int*   offsets = (int*)d_ws + 24;
    int*   cursor  = (int*)d_ws + 32;
    int*   sel     = (int*)d_ws + 40;
    int*   perm    = (int*)d_ws + 40 + 1024;
    unsigned short* hmid = (unsigned short*)((char*)d_ws + 8704);

    hipMemsetAsync(d_ws, 0, 160, stream);
    gate_kernel<<<64, 256, 0, stream>>>(x, gw, gb, gsum, gsumsq, count, sel);
    finalize_kernel<<<1, 64, 0, stream>>>(gsum, gsumsq, count, offsets, cursor, out + (long)Tn * Hdim);
    scatter_kernel<<<4, 256, 0, stream>>>(sel, cursor, perm);
    gemm1_kernel<<<dim3(48, 2, 8), 256, 0, stream>>>(x, w1, b1, count, offsets, perm, hmid);
    gemm2_kernel<<<dim3(24, 2, 8), 256, 0, stream>>>(hmid, w2, b2, count, offsets, perm, out);
}

// Round 3
// 240.462 us; speedup vs baseline: 1.2720x; 1.2497x over previous
//
#include <hip/hip_runtime.h>
#include <hip/hip_bf16.h>
#include <math.h>

#define Hdim 768
#define Idim 3072
#define Tn   1024
#define En   8
#define LD1  72    // Bs stride gemm1 (shorts): 144 B ≡ 4 banks (mod 32)
#define LD2  136   // Bs stride gemm2 (shorts): 272 B ≡ 4 banks (mod 32)

using v4f     = __attribute__((ext_vector_type(4))) float;
using short8  = __attribute__((ext_vector_type(8))) short;
using short4v = __attribute__((ext_vector_type(4))) short;

__device__ inline unsigned short f2bf(float f) {
    unsigned u = __float_as_uint(f);
    u += 0x7fffu + ((u >> 16) & 1u);   // RNE
    return (unsigned short)(u >> 16);
}
__device__ inline short4v pack4(float4 v) {
    return short4v{ (short)f2bf(v.x), (short)f2bf(v.y), (short)f2bf(v.z), (short)f2bf(v.w) };
}
__device__ __forceinline__ void gl2lds16(const unsigned short* g, unsigned short* l) {
    __builtin_amdgcn_global_load_lds(
        (const __attribute__((address_space(1))) void*)g,
        (__attribute__((address_space(3))) void*)l, 16, 0, 0);
}

// ---------------- gate: logits (fp32), argmax, per-expert sum/sumsq ----------------
__global__ __launch_bounds__(256) void gate_kernel(
    const float* __restrict__ x, const float* __restrict__ gw, const float* __restrict__ gb,
    float* __restrict__ gsum, float* __restrict__ gsumsq,
    int* __restrict__ count, int* __restrict__ sel)
{
    __shared__ float gws[8 * 772];
    __shared__ float lg[8][8];
    int tid = threadIdx.x;
    long t0 = (long)blockIdx.x * 8;
    for (int i = tid; i < 8 * 768; i += 256) gws[(i / 768) * 772 + (i % 768)] = gw[i];
    __syncthreads();

    int tok = tid >> 5, e = (tid >> 2) & 7, qr = tid & 3;
    const float4* xp = (const float4*)(x + (t0 + tok) * Hdim) + qr * 48;
    const float4* gp = (const float4*)(gws + e * 772) + qr * 48;
    float a0 = 0.f, a1 = 0.f;
#pragma unroll 8
    for (int i = 0; i < 48; i += 2) {
        float4 xa = xp[i], ga = gp[i], xc = xp[i + 1], gc = gp[i + 1];
        a0 += xa.x * ga.x + xa.y * ga.y + xa.z * ga.z + xa.w * ga.w;
        a1 += xc.x * gc.x + xc.y * gc.y + xc.z * gc.z + xc.w * gc.w;
    }
    float acc = a0 + a1;
    acc += __shfl_xor(acc, 1);
    acc += __shfl_xor(acc, 2);
    if (qr == 0) lg[tok][e] = acc + gb[e];
    __syncthreads();

    if (tid < 8) {
        float best = lg[tid][0]; int bi = 0;
        for (int j = 1; j < 8; j++) { float v = lg[tid][j]; if (v > best) { best = v; bi = j; } }
        sel[t0 + tid] = bi;
        atomicAdd(&count[bi], 1);
    } else if (tid < 16) {
        int e2 = tid - 8;
        float s = 0.f, ss = 0.f;
        for (int t2 = 0; t2 < 8; t2++) { float v = lg[t2][e2]; s += v; ss += v * v; }
        atomicAdd(&gsum[e2], s);
        atomicAdd(&gsumsq[e2], ss);
    }
}

// ---------------- finalize ----------------
__global__ void finalize_kernel(const float* __restrict__ gsum, const float* __restrict__ gsumsq,
                                const int* __restrict__ count,
                                int* __restrict__ offsets, int* __restrict__ cursor,
                                float* __restrict__ out_lb)
{
    if (threadIdx.x == 0) {
        float accr = 0.f;
        for (int e = 0; e < 8; e++) {
            float mean = gsum[e] * (1.0f / 1024.0f);
            float var  = (gsumsq[e] - gsum[e] * mean) * (1.0f / 1023.0f);
            accr += var / (mean * mean + 1e-8f);
        }
        out_lb[0] = 0.01f * accr * 0.125f;
        int off = 0;
        for (int e = 0; e < 8; e++) { offsets[e] = off; cursor[e] = off; off += count[e]; }
    }
}

// ---------------- scatter ----------------
__global__ __launch_bounds__(256) void scatter_kernel(const int* __restrict__ sel,
                                                      int* __restrict__ cursor,
                                                      int* __restrict__ perm)
{
    int t = blockIdx.x * 256 + threadIdx.x;
    if (t < Tn) {
        int e = sel[t];
        int pos = atomicAdd(&cursor[e], 1);
        perm[pos] = t;
    }
}

// ---------------- gather x -> bf16, bucket order ----------------
__global__ __launch_bounds__(256) void gather_x_kernel(const float* __restrict__ x,
                                                       const int* __restrict__ perm,
                                                       unsigned short* __restrict__ xb)
{
    int slot = blockIdx.x * 4 + (threadIdx.x >> 6);
    int lane = threadIdx.x & 63;
    int t = perm[slot];
    const float4* src = (const float4*)(x + (long)t * Hdim);
    unsigned short* dst = xb + (long)slot * Hdim;
#pragma unroll
    for (int i = 0; i < 3; i++) {
        int c = lane + 64 * i;
        *(short4v*)(dst + c * 4) = pack4(src[c]);
    }
}

// ---------------- init out with b2[sel[t]] ----------------
__global__ __launch_bounds__(256) void init_out_kernel(const float* __restrict__ b2,
                                                       const int* __restrict__ sel,
                                                       float* __restrict__ out)
{
    int t = blockIdx.x;
    int h = blockIdx.y * 256 + threadIdx.x;
    out[(long)t * Hdim + h] = b2[sel[t] * Hdim + h];
}

// ---------------- GEMM1: hmid = gelu(xb @ w1^T + b1) -> bf16 ----------------
// tile 128(M) x 32(N), BK=64, grid (96, 2, 8): 768 active blocks
__global__ __launch_bounds__(256) void gemm1_kernel(
    const unsigned short* __restrict__ xb, const float* __restrict__ w1, const float* __restrict__ b1,
    const int* __restrict__ count, const int* __restrict__ offsets,
    unsigned short* __restrict__ hmid)
{
    int e = blockIdx.z;
    int nloc = count[e];
    int m0 = blockIdx.y << 7;
    if (m0 >= nloc) return;
    int n0 = blockIdx.x << 5;
    int off = offsets[e];

    __shared__ __align__(16) unsigned short As[128 * 64];   // 16 KB, XOR-swizzled chunks
    __shared__ __align__(16) unsigned short Bs[32 * LD1];   // 4.5 KB

    int tid = threadIdx.x;
    int lane = tid & 63, wave = tid >> 6;
    int quad = lane >> 4, l16 = lane & 15;
    int wm = wave << 5;

    // A staging: 1024 16B-chunks, 16 wave-instr groups, 4 per wave
    const unsigned short* aG[4];
    unsigned short* aL[4];
#pragma unroll
    for (int i = 0; i < 4; i++) {
        int p = (wave * 4 + i) * 64 + lane;
        int row = p >> 3;
        int kc = (p & 7) ^ (row & 7);
        int m = m0 + row; int mm = m < nloc ? m : nloc - 1;
        aG[i] = xb + (long)(off + mm) * Hdim + kc * 8;
        aL[i] = (unsigned short*)As + p * 8;
    }
    // B: 32 rows x 64 fp32; kq col(16 float4), rows rb, rb+16
    int kq = tid & 15, rb = tid >> 4;
    const float* bp0 = w1 + ((long)e * Idim + n0 + rb) * Hdim + kq * 4;
    const float* bp1 = bp0 + (long)16 * Hdim;

    v4f acc[2][2];
#pragma unroll
    for (int i = 0; i < 2; i++)
#pragma unroll
        for (int j = 0; j < 2; j++) acc[i][j] = (v4f){0.f, 0.f, 0.f, 0.f};

    float4 nb0 = *(const float4*)bp0;
    float4 nb1 = *(const float4*)bp1;

    for (int kb = 0; kb < Hdim; kb += 64) {
        __syncthreads();                                   // prev-iter LDS reads done
#pragma unroll
        for (int i = 0; i < 4; i++) gl2lds16(aG[i] + kb, aL[i]);
        *(short4v*)(Bs + rb * LD1 + kq * 4)        = pack4(nb0);
        *(short4v*)(Bs + (rb + 16) * LD1 + kq * 4) = pack4(nb1);
        __syncthreads();                                   // A landed + Bs visible
        if (kb + 64 < Hdim) {                              // prefetch next B (overlaps MFMA)
            nb0 = *(const float4*)(bp0 + kb + 64);
            nb1 = *(const float4*)(bp1 + kb + 64);
        }
#pragma unroll
        for (int s = 0; s < 2; s++) {
            short8 af[2], bf2[2];
#pragma unroll
            for (int i = 0; i < 2; i++) {
                int r = wm + i * 16 + l16;
                af[i] = *(const short8*)(As + r * 64 + (((s * 4 + quad) ^ (r & 7)) * 8));
            }
#pragma unroll
            for (int j = 0; j < 2; j++)
                bf2[j] = *(const short8*)(Bs + (j * 16 + l16) * LD1 + s * 32 + quad * 8);
#pragma unroll
            for (int i = 0; i < 2; i++)
#pragma unroll
                for (int j = 0; j < 2; j++)
                    acc[i][j] = __builtin_amdgcn_mfma_f32_16x16x32_bf16(af[i], bf2[j], acc[i][j], 0, 0, 0);
        }
    }

#pragma unroll
    for (int i = 0; i < 2; i++) {
        int mr = wm + i * 16 + quad * 4;
#pragma unroll
        for (int r = 0; r < 4; r++) {
            int m = m0 + mr + r;
            if (m >= nloc) continue;
            long slot = off + m;
#pragma unroll
            for (int j = 0; j < 2; j++) {
                int n = n0 + j * 16 + l16;
                float v = acc[i][j][r] + b1[e * Idim + n];
                float g = 0.5f * v * (1.0f + erff(v * 0.70710678118654752f));
                hmid[slot * Idim + n] = f2bf(g);
            }
        }
    }
}

// ---------------- GEMM2: out[t] += hmid @ w2^T (split-K=4, atomics) ----------------
// tile 128(M) x 32(N), BK=128, K-chunk 768, grid (96, 2, 8): 768 active blocks
__global__ __launch_bounds__(256) void gemm2_kernel(
    const unsigned short* __restrict__ hmid, const float* __restrict__ w2,
    const int* __restrict__ count, const int* __restrict__ offsets,
    const int* __restrict__ perm, float* __restrict__ out)
{
    int e = blockIdx.z;
    int nloc = count[e];
    int m0 = blockIdx.y << 7;
    if (m0 >= nloc) return;
    int bx = blockIdx.x;
    int n0 = (bx % 24) << 5;
    long kbase = (long)(bx / 24) * 768;
    int off = offsets[e];

    __shared__ __align__(16) unsigned short As[128 * 128];  // 32 KB, XOR-swizzled chunks
    __shared__ __align__(16) unsigned short Bs[32 * LD2];   //  8.7 KB

    int tid = threadIdx.x;
    int lane = tid & 63, wave = tid >> 6;
    int quad = lane >> 4, l16 = lane & 15;
    int wm = wave << 5;

    // A staging: 2048 chunks, 32 groups, 8 per wave
    const unsigned short* aG[8];
    unsigned short* aL[8];
#pragma unroll
    for (int i = 0; i < 8; i++) {
        int p = (wave * 8 + i) * 64 + lane;
        int row = p >> 4;
        int kc = (p & 15) ^ (row & 15);
        int m = m0 + row; int mm = m < nloc ? m : nloc - 1;
        aG[i] = hmid + (long)(off + mm) * Idim + kbase + kc * 8;
        aL[i] = (unsigned short*)As + p * 8;
    }
    // B: 32 rows x 128 fp32; kq5 col(32 float4), rows rb8 + 8s
    int kq5 = tid & 31, rb8 = tid >> 5;
    const float* bp[4];
#pragma unroll
    for (int s = 0; s < 4; s++)
        bp[s] = w2 + ((long)e * Hdim + n0 + rb8 + 8 * s) * Idim + kbase + kq5 * 4;

    v4f acc[2][2];
#pragma unroll
    for (int i = 0; i < 2; i++)
#pragma unroll
        for (int j = 0; j < 2; j++) acc[i][j] = (v4f){0.f, 0.f, 0.f, 0.f};

    float4 nb[4];
#pragma unroll
    for (int s = 0; s < 4; s++) nb[s] = *(const float4*)bp[s];

    for (int kb = 0; kb < 768; kb += 128) {
        __syncthreads();
#pragma unroll
        for (int i = 0; i < 8; i++) gl2lds16(aG[i] + kb, aL[i]);
#pragma unroll
        for (int s = 0; s < 4; s++)
            *(short4v*)(Bs + (rb8 + 8 * s) * LD2 + kq5 * 4) = pack4(nb[s]);
        __syncthreads();
        if (kb + 128 < 768) {
#pragma unroll
            for (int s = 0; s < 4; s++) nb[s] = *(const float4*)(bp[s] + kb + 128);
        }
#pragma unroll
        for (int s = 0; s < 4; s++) {
            short8 af[2], bf2[2];
#pragma unroll
            for (int i = 0; i < 2; i++) {
                int r = wm + i * 16 + l16;
                af[i] = *(const short8*)(As + r * 128 + (((s * 4 + quad) ^ (r & 15)) * 8));
            }
#pragma unroll
            for (int j = 0; j < 2; j++)
                bf2[j] = *(const short8*)(Bs + (j * 16 + l16) * LD2 + s * 32 + quad * 8);
#pragma unroll
            for (int i = 0; i < 2; i++)
#pragma unroll
                for (int j = 0; j < 2; j++)
                    acc[i][j] = __builtin_amdgcn_mfma_f32_16x16x32_bf16(af[i], bf2[j], acc[i][j], 0, 0, 0);
        }
    }

#pragma unroll
    for (int i = 0; i < 2; i++) {
        int mr = wm + i * 16 + quad * 4;
#pragma unroll
        for (int r = 0; r < 4; r++) {
            int m = m0 + mr + r;
            if (m >= nloc) continue;
            int t = perm[off + m];
#pragma unroll
            for (int j = 0; j < 2; j++) {
                int n = n0 + j * 16 + l16;
                atomicAdd(out + (long)t * Hdim + n, acc[i][j][r]);
            }
        }
    }
}

extern "C" void kernel_launch(void* const* d_in, const int* in_sizes, int n_in,
                              void* d_out, int out_size, void* d_ws, size_t ws_size,
                              hipStream_t stream)
{
    const float* x  = (const float*)d_in[0];
    const float* gw = (const float*)d_in[1];
    const float* gb = (const float*)d_in[2];
    const float* w1 = (const float*)d_in[3];
    const float* b1 = (const float*)d_in[4];
    const float* w2 = (const float*)d_in[5];
    const float* b2 = (const float*)d_in[6];
    float* out = (float*)d_out;

    float* gsum    = (float*)d_ws;
    float* gsumsq  = gsum + 8;
    int*   count   = (int*)d_ws + 16;
    int*   offsets = (int*)d_ws + 24;
    int*   cursor  = (int*)d_ws + 32;
    int*   sel     = (int*)d_ws + 40;
    int*   perm    = (int*)d_ws + 40 + 1024;
    unsigned short* xb   = (unsigned short*)((char*)d_ws + 8704);
    unsigned short* hmid = (unsigned short*)((char*)d_ws + 8704 + (size_t)Tn * Hdim * 2);

    hipMemsetAsync(d_ws, 0, 160, stream);
    gate_kernel<<<128, 256, 0, stream>>>(x, gw, gb, gsum, gsumsq, count, sel);
    finalize_kernel<<<1, 64, 0, stream>>>(gsum, gsumsq, count, offsets, cursor, out + (long)Tn * Hdim);
    scatter_kernel<<<4, 256, 0, stream>>>(sel, cursor, perm);
    gather_x_kernel<<<256, 256, 0, stream>>>(x, perm, xb);
    init_out_kernel<<<dim3(Tn, 3), 256, 0, stream>>>(b2, sel, out);
    gemm1_kernel<<<dim3(96, 2, 8), 256, 0, stream>>>(xb, w1, b1, count, offsets, hmid);
    gemm2_kernel<<<dim3(96, 2, 8), 256, 0, stream>>>(hmid, w2, count, offsets, perm, out);
}

// Round 4
// 231.209 us; speedup vs baseline: 1.3229x; 1.0400x over previous
//
#include <hip/hip_runtime.h>
#include <hip/hip_bf16.h>
#include <math.h>

#define Hdim 768
#define Idim 3072
#define Tn   1024
#define En   8
#define LD1  72    // Bs stride (shorts), BK=64: 144 B ≡ 4 banks (mod 32)
#define LD2  136   // Bs stride (shorts), BK=128: 272 B ≡ 4 banks (mod 32)

using v4f     = __attribute__((ext_vector_type(4))) float;
using short8  = __attribute__((ext_vector_type(8))) short;
using short4v = __attribute__((ext_vector_type(4))) short;

__device__ inline unsigned short f2bf(float f) {
    unsigned u = __float_as_uint(f);
    u += 0x7fffu + ((u >> 16) & 1u);   // RNE
    return (unsigned short)(u >> 16);
}
__device__ inline short4v pack4(float4 v) {
    return short4v{ (short)f2bf(v.x), (short)f2bf(v.y), (short)f2bf(v.z), (short)f2bf(v.w) };
}
__device__ __forceinline__ void gl2lds16(const unsigned short* g, unsigned short* l) {
    __builtin_amdgcn_global_load_lds(
        (const __attribute__((address_space(1))) void*)g,
        (__attribute__((address_space(3))) void*)l, 16, 0, 0);
}

// ---------------- gate ----------------
__global__ __launch_bounds__(256) void gate_kernel(
    const float* __restrict__ x, const float* __restrict__ gw, const float* __restrict__ gb,
    float* __restrict__ gsum, float* __restrict__ gsumsq,
    int* __restrict__ count, int* __restrict__ sel)
{
    __shared__ float gws[8 * 772];
    __shared__ float lg[8][8];
    int tid = threadIdx.x;
    long t0 = (long)blockIdx.x * 8;
    for (int i = tid; i < 8 * 768; i += 256) gws[(i / 768) * 772 + (i % 768)] = gw[i];
    __syncthreads();

    int tok = tid >> 5, e = (tid >> 2) & 7, qr = tid & 3;
    const float4* xp = (const float4*)(x + (t0 + tok) * Hdim) + qr * 48;
    const float4* gp = (const float4*)(gws + e * 772) + qr * 48;
    float a0 = 0.f, a1 = 0.f;
#pragma unroll 8
    for (int i = 0; i < 48; i += 2) {
        float4 xa = xp[i], ga = gp[i], xc = xp[i + 1], gc = gp[i + 1];
        a0 += xa.x * ga.x + xa.y * ga.y + xa.z * ga.z + xa.w * ga.w;
        a1 += xc.x * gc.x + xc.y * gc.y + xc.z * gc.z + xc.w * gc.w;
    }
    float acc = a0 + a1;
    acc += __shfl_xor(acc, 1);
    acc += __shfl_xor(acc, 2);
    if (qr == 0) lg[tok][e] = acc + gb[e];
    __syncthreads();

    if (tid < 8) {
        float best = lg[tid][0]; int bi = 0;
        for (int j = 1; j < 8; j++) { float v = lg[tid][j]; if (v > best) { best = v; bi = j; } }
        sel[t0 + tid] = bi;
        atomicAdd(&count[bi], 1);
    } else if (tid < 16) {
        int e2 = tid - 8;
        float s = 0.f, ss = 0.f;
        for (int t2 = 0; t2 < 8; t2++) { float v = lg[t2][e2]; s += v; ss += v * v; }
        atomicAdd(&gsum[e2], s);
        atomicAdd(&gsumsq[e2], ss);
    }
}

// ---------------- finalize + scatter (single block, 1024 threads) ----------------
__global__ __launch_bounds__(1024) void finscat_kernel(
    const float* __restrict__ gsum, const float* __restrict__ gsumsq,
    const int* __restrict__ count, int* __restrict__ offsets,
    const int* __restrict__ sel, int* __restrict__ perm,
    float* __restrict__ out_lb)
{
    __shared__ int lcur[8];
    int tid = threadIdx.x;
    if (tid == 0) {
        float accr = 0.f;
        for (int e = 0; e < 8; e++) {
            float mean = gsum[e] * (1.0f / 1024.0f);
            float var  = (gsumsq[e] - gsum[e] * mean) * (1.0f / 1023.0f);  // ddof=1
            accr += var / (mean * mean + 1e-8f);
        }
        out_lb[0] = 0.01f * accr * 0.125f;
        int off = 0;
        for (int e = 0; e < 8; e++) { offsets[e] = off; lcur[e] = off; off += count[e]; }
    }
    __syncthreads();
    int e = sel[tid];
    int pos = atomicAdd(&lcur[e], 1);
    perm[pos] = tid;
}

// ---------------- gather x->bf16 bucket order + init out with b2 ----------------
__global__ __launch_bounds__(256) void gather_init_kernel(
    const float* __restrict__ x, const float* __restrict__ b2,
    const int* __restrict__ perm, const int* __restrict__ sel,
    unsigned short* __restrict__ xb, float* __restrict__ out)
{
    int slot = blockIdx.x * 4 + (threadIdx.x >> 6);
    int lane = threadIdx.x & 63;
    int t = perm[slot];
    int e = sel[t];
    const float4* src = (const float4*)(x + (long)t * Hdim);
    const float4* bsrc = (const float4*)(b2 + (long)e * Hdim);
    unsigned short* dst = xb + (long)slot * Hdim;
    float4* odst = (float4*)(out + (long)t * Hdim);
#pragma unroll
    for (int i = 0; i < 3; i++) {
        int c = lane + 64 * i;
        *(short4v*)(dst + c * 4) = pack4(src[c]);
        odst[c] = bsrc[c];
    }
}

// ---------------- GEMM1: hmid = gelu(xb @ w1^T + b1) -> bf16 ----------------
// tile 64(M) x 32(N), BK=64, grid (96, 4, 8): ~1630 live blocks
__global__ __launch_bounds__(256) void gemm1_kernel(
    const unsigned short* __restrict__ xb, const float* __restrict__ w1, const float* __restrict__ b1,
    const int* __restrict__ count, const int* __restrict__ offsets,
    unsigned short* __restrict__ hmid)
{
    int e = blockIdx.z;
    int nloc = count[e];
    int m0 = blockIdx.y << 6;
    if (m0 >= nloc) return;
    int n0 = blockIdx.x << 5;
    int off = offsets[e];

    __shared__ __align__(16) unsigned short As[64 * 64];    // 8 KB, XOR-swizzled chunks
    __shared__ __align__(16) unsigned short Bs[32 * LD1];   // 4.5 KB

    int tid = threadIdx.x;
    int lane = tid & 63, wave = tid >> 6;
    int quad = lane >> 4, l16 = lane & 15;
    int wm = wave << 4;                                     // wave tile 16(M) x 32(N)

    // A staging: 512 16B-chunks, 2 per thread, lane-contiguous LDS dest
    const unsigned short* aG[2];
    unsigned short* aL[2];
#pragma unroll
    for (int i = 0; i < 2; i++) {
        int p = (wave * 2 + i) * 64 + lane;
        int row = p >> 3;
        int kc = (p & 7) ^ (row & 7);
        int m = m0 + row; int mm = m < nloc ? m : nloc - 1;
        aG[i] = xb + (long)(off + mm) * Hdim + kc * 8;
        aL[i] = (unsigned short*)As + p * 8;
    }
    // B: 32 rows x 64 fp32
    int kq = tid & 15, rb = tid >> 4;
    const float* bp0 = w1 + ((long)e * Idim + n0 + rb) * Hdim + kq * 4;
    const float* bp1 = bp0 + (long)16 * Hdim;

    v4f acc[2];
    acc[0] = (v4f){0.f, 0.f, 0.f, 0.f};
    acc[1] = (v4f){0.f, 0.f, 0.f, 0.f};

    float4 nb0 = *(const float4*)bp0;
    float4 nb1 = *(const float4*)bp1;

    for (int kb = 0; kb < Hdim; kb += 64) {
        __syncthreads();
#pragma unroll
        for (int i = 0; i < 2; i++) gl2lds16(aG[i] + kb, aL[i]);
        *(short4v*)(Bs + rb * LD1 + kq * 4)        = pack4(nb0);
        *(short4v*)(Bs + (rb + 16) * LD1 + kq * 4) = pack4(nb1);
        __syncthreads();
        if (kb + 64 < Hdim) {
            nb0 = *(const float4*)(bp0 + kb + 64);
            nb1 = *(const float4*)(bp1 + kb + 64);
        }
#pragma unroll
        for (int s = 0; s < 2; s++) {
            int r = wm + l16;
            short8 af = *(const short8*)(As + r * 64 + (((s * 4 + quad) ^ (r & 7)) * 8));
            short8 bf2[2];
#pragma unroll
            for (int j = 0; j < 2; j++)
                bf2[j] = *(const short8*)(Bs + (j * 16 + l16) * LD1 + s * 32 + quad * 8);
#pragma unroll
            for (int j = 0; j < 2; j++)
                acc[j] = __builtin_amdgcn_mfma_f32_16x16x32_bf16(af, bf2[j], acc[j], 0, 0, 0);
        }
    }

    int mr = wm + quad * 4;
#pragma unroll
    for (int r = 0; r < 4; r++) {
        int m = m0 + mr + r;
        if (m >= nloc) continue;
        long slot = off + m;
#pragma unroll
        for (int j = 0; j < 2; j++) {
            int n = n0 + j * 16 + l16;
            float v = acc[j][r] + b1[e * Idim + n];
            float g = 0.5f * v * (1.0f + erff(v * 0.70710678118654752f));
            hmid[slot * Idim + n] = f2bf(g);
        }
    }
}

// ---------------- GEMM2: out[t] += hmid @ w2^T (split-K=4, atomics) ----------------
// tile 64(M) x 32(N), BK=128, K-chunk 768, grid (96, 4, 8): ~1630 live blocks
__global__ __launch_bounds__(256) void gemm2_kernel(
    const unsigned short* __restrict__ hmid, const float* __restrict__ w2,
    const int* __restrict__ count, const int* __restrict__ offsets,
    const int* __restrict__ perm, float* __restrict__ out)
{
    int e = blockIdx.z;
    int nloc = count[e];
    int m0 = blockIdx.y << 6;
    if (m0 >= nloc) return;
    int bx = blockIdx.x;
    int n0 = (bx % 24) << 5;
    long kbase = (long)(bx / 24) * 768;
    int off = offsets[e];

    __shared__ __align__(16) unsigned short As[64 * 128];   // 16 KB, XOR-swizzled chunks
    __shared__ __align__(16) unsigned short Bs[32 * LD2];   //  8.7 KB

    int tid = threadIdx.x;
    int lane = tid & 63, wave = tid >> 6;
    int quad = lane >> 4, l16 = lane & 15;
    int wm = wave << 4;                                     // wave tile 16 x 32

    // A staging: 1024 chunks, 4 per thread
    const unsigned short* aG[4];
    unsigned short* aL[4];
#pragma unroll
    for (int i = 0; i < 4; i++) {
        int p = (wave * 4 + i) * 64 + lane;
        int row = p >> 4;
        int kc = (p & 15) ^ (row & 15);
        int m = m0 + row; int mm = m < nloc ? m : nloc - 1;
        aG[i] = hmid + (long)(off + mm) * Idim + kbase + kc * 8;
        aL[i] = (unsigned short*)As + p * 8;
    }
    // B: 32 rows x 128 fp32
    int kq5 = tid & 31, rb8 = tid >> 5;
    const float* bp[4];
#pragma unroll
    for (int s = 0; s < 4; s++)
        bp[s] = w2 + ((long)e * Hdim + n0 + rb8 + 8 * s) * Idim + kbase + kq5 * 4;

    v4f acc[2];
    acc[0] = (v4f){0.f, 0.f, 0.f, 0.f};
    acc[1] = (v4f){0.f, 0.f, 0.f, 0.f};

    float4 nb[4];
#pragma unroll
    for (int s = 0; s < 4; s++) nb[s] = *(const float4*)bp[s];

    for (int kb = 0; kb < 768; kb += 128) {
        __syncthreads();
#pragma unroll
        for (int i = 0; i < 4; i++) gl2lds16(aG[i] + kb, aL[i]);
#pragma unroll
        for (int s = 0; s < 4; s++)
            *(short4v*)(Bs + (rb8 + 8 * s) * LD2 + kq5 * 4) = pack4(nb[s]);
        __syncthreads();
        if (kb + 128 < 768) {
#pragma unroll
            for (int s = 0; s < 4; s++) nb[s] = *(const float4*)(bp[s] + kb + 128);
        }
#pragma unroll
        for (int s = 0; s < 4; s++) {
            int r = wm + l16;
            short8 af = *(const short8*)(As + r * 128 + (((s * 4 + quad) ^ (r & 15)) * 8));
            short8 bf2[2];
#pragma unroll
            for (int j = 0; j < 2; j++)
                bf2[j] = *(const short8*)(Bs + (j * 16 + l16) * LD2 + s * 32 + quad * 8);
#pragma unroll
            for (int j = 0; j < 2; j++)
                acc[j] = __builtin_amdgcn_mfma_f32_16x16x32_bf16(af, bf2[j], acc[j], 0, 0, 0);
        }
    }

    int mr = wm + quad * 4;
#pragma unroll
    for (int r = 0; r < 4; r++) {
        int m = m0 + mr + r;
        if (m >= nloc) continue;
        int t = perm[off + m];
#pragma unroll
        for (int j = 0; j < 2; j++) {
            int n = n0 + j * 16 + l16;
            atomicAdd(out + (long)t * Hdim + n, acc[j][r]);
        }
    }
}

extern "C" void kernel_launch(void* const* d_in, const int* in_sizes, int n_in,
                              void* d_out, int out_size, void* d_ws, size_t ws_size,
                              hipStream_t stream)
{
    const float* x  = (const float*)d_in[0];
    const float* gw = (const float*)d_in[1];
    const float* gb = (const float*)d_in[2];
    const float* w1 = (const float*)d_in[3];
    const float* b1 = (const float*)d_in[4];
    const float* w2 = (const float*)d_in[5];
    const float* b2 = (const float*)d_in[6];
    float* out = (float*)d_out;

    float* gsum    = (float*)d_ws;
    float* gsumsq  = gsum + 8;
    int*   count   = (int*)d_ws + 16;
    int*   offsets = (int*)d_ws + 24;
    int*   sel     = (int*)d_ws + 40;
    int*   perm    = (int*)d_ws + 40 + 1024;
    unsigned short* xb   = (unsigned short*)((char*)d_ws + 8704);
    unsigned short* hmid = (unsigned short*)((char*)d_ws + 8704 + (size_t)Tn * Hdim * 2);

    hipMemsetAsync(d_ws, 0, 160, stream);
    gate_kernel<<<128, 256, 0, stream>>>(x, gw, gb, gsum, gsumsq, count, sel);
    finscat_kernel<<<1, 1024, 0, stream>>>(gsum, gsumsq, count, offsets, sel, perm,
                                           out + (long)Tn * Hdim);
    gather_init_kernel<<<256, 256, 0, stream>>>(x, b2, perm, sel, xb, out);
    gemm1_kernel<<<dim3(96, 4, 8), 256, 0, stream>>>(xb, w1, b1, count, offsets, hmid);
    gemm2_kernel<<<dim3(96, 4, 8), 256, 0, stream>>>(hmid, w2, count, offsets, perm, out);
}